// Round 27
// baseline (95.843 us; speedup 1.0000x reference)
//
#include <hip/hip_runtime.h>

#define N_NODES 20000
#define N_EDGES 160000
#define N_PAIRS 50000
#define DMAX 32
// F_IN = CHANNELS = 32, EDGE_DIM = 8; G row = 288 floats (knw 256 + knb 32)

__device__ __forceinline__ float4 f4fma(float s, float4 w, float4 a) {
    a.x += s * w.x; a.y += s * w.y; a.z += s * w.z; a.w += s * w.w;
    return a;
}

__device__ __forceinline__ float bf2f(unsigned int u) {  // low 16 bits = bf16
    return __uint_as_float(u << 16);
}
__device__ __forceinline__ unsigned int f2bf(float f) {  // RNE, low 16 bits
    unsigned int u = __float_as_uint(f);
    u += 0x7fffu + ((u >> 16) & 1u);
    return u >> 16;
}

__global__ void zero_cnt(int* __restrict__ c) {
    int t = blockIdx.x * blockDim.x + threadIdx.x;
    if (t < N_NODES) c[t] = 0;
}

// adjacency by target: slot -> src (int) + bf16-packed E row (uint4, 16B).
__global__ __launch_bounds__(256) void fill_adj(const int* __restrict__ ei,
                                                const float* __restrict__ E,
                                                int* __restrict__ cnt,
                                                int* __restrict__ adjsrc,
                                                uint4* __restrict__ adjEb) {
    int e = blockIdx.x * blockDim.x + threadIdx.x;
    if (e >= N_EDGES) return;
    int2 st = ((const int2*)ei)[e];  // x = src, y = tgt
    int slot = atomicAdd(&cnt[st.y], 1);
    if (slot < DMAX) {
        int idx = (st.y << 5) + slot;
        adjsrc[idx] = st.x;
        const float4* e4 = (const float4*)(E + (size_t)e * 8);
        float4 a = e4[0], b = e4[1];
        uint4 p;
        p.x = f2bf(a.x) | (f2bf(a.y) << 16);
        p.y = f2bf(a.z) | (f2bf(a.w) << 16);
        p.z = f2bf(b.x) | (f2bf(b.y) << 16);
        p.w = f2bf(b.z) | (f2bf(b.w) << 16);
        adjEb[idx] = p;
    }
}

#define EDGE_FMA_P(p, xv)                                                      \
    g0 += bf2f((p).x & 0xffffu) * (xv); g1 += bf2f((p).x >> 16) * (xv);        \
    g2 += bf2f((p).y & 0xffffu) * (xv); g3 += bf2f((p).y >> 16) * (xv);        \
    g4 += bf2f((p).z & 0xffffu) * (xv); g5 += bf2f((p).z >> 16) * (xv);        \
    g6 += bf2f((p).w & 0xffffu) * (xv); g7 += bf2f((p).w >> 16) * (xv);        \
    g8 += (xv);

// G gather (R14/R18-validated): ONE WAVE PER NODE; chunks of 8 edges (4 per
// half), independent slot/E/X loads issued before FMAs.
__global__ __launch_bounds__(256) void edge_gather(const float* __restrict__ X,
                                                   const int* __restrict__ cnt,
                                                   const int* __restrict__ adjsrc,
                                                   const uint4* __restrict__ adjEb,
                                                   float* __restrict__ G) {
    int t = blockIdx.x * blockDim.x + threadIdx.x;
    int n = t >> 6;
    if (n >= N_NODES) return;
    int lane = t & 63;
    int i = lane & 31;
    int half = lane >> 5;

    int deg = min(cnt[n], DMAX);
    int base = n << 5;
    float g0 = 0.f, g1 = 0.f, g2 = 0.f, g3 = 0.f;
    float g4 = 0.f, g5 = 0.f, g6 = 0.f, g7 = 0.f, g8 = 0.f;

    int c = 0;
    for (; c + 8 <= deg; c += 8) {
        int k0 = base + c + half * 4;
        int s0 = adjsrc[k0 + 0];
        int s1 = adjsrc[k0 + 1];
        int s2 = adjsrc[k0 + 2];
        int s3 = adjsrc[k0 + 3];
        uint4 p0 = adjEb[k0 + 0];
        uint4 p1 = adjEb[k0 + 1];
        uint4 p2 = adjEb[k0 + 2];
        uint4 p3 = adjEb[k0 + 3];
        float xv0 = X[s0 * 32 + i];
        float xv1 = X[s1 * 32 + i];
        float xv2 = X[s2 * 32 + i];
        float xv3 = X[s3 * 32 + i];
        EDGE_FMA_P(p0, xv0);
        EDGE_FMA_P(p1, xv1);
        EDGE_FMA_P(p2, xv2);
        EDGE_FMA_P(p3, xv3);
    }
    for (int k = c + half; k < deg; k += 2) {
        int s = adjsrc[base + k];
        uint4 p = adjEb[base + k];
        float xv = X[s * 32 + i];
        EDGE_FMA_P(p, xv);
    }

    g0 += __shfl_xor(g0, 32); g1 += __shfl_xor(g1, 32);
    g2 += __shfl_xor(g2, 32); g3 += __shfl_xor(g3, 32);
    g4 += __shfl_xor(g4, 32); g5 += __shfl_xor(g5, 32);
    g6 += __shfl_xor(g6, 32); g7 += __shfl_xor(g7, 32);
    g8 += __shfl_xor(g8, 32);

    if (half == 0) {
        float* gr = G + (size_t)n * 288;
        gr[0 * 32 + i] = g0; gr[1 * 32 + i] = g1;
        gr[2 * 32 + i] = g2; gr[3 * 32 + i] = g3;
        gr[4 * 32 + i] = g4; gr[5 * 32 + i] = g5;
        gr[6 * 32 + i] = g6; gr[7 * 32 + i] = g7;
        gr[256 + i] = g8;
    }
}

// Epilogue GEMM (R26): K-SPLIT x Mr=4 + bf16 W' + COALESCED LDS-staged G.
//   out[n][o] = sum_k Gext[n][k]*W'[k][o]; Gext = [G row (288) | X row (32)].
// Staging: 2560 float4 read ROW-MAJOR coalesced (full 64B lines, ~4-8x fewer
// L2 transactions than the scattered per-mg reads), written k-major into
// Gt[k][node] stride 33 (write banks spread; inner b32 reads conflict-free
// 8-lane broadcasts). W' bf16 in LDS (R25-validated unpack).
// 256 thr = 4 waves; wave ks owns k4 in [ks*20, ks*20+20); thread (mg,jg) ->
// nodes mg*4..+3 x outs 4jg..+3 partials; LDS parts reduce (R24-validated).
// LDS: 20480 + 42240 + 16384 = 79,104B -> 2 blocks/CU. 625 blocks x 32 nodes.
__global__ __launch_bounds__(256) void epi_gemm(const float4* __restrict__ G4,
                                                const float4* __restrict__ X4,
                                                const float4* __restrict__ knw4,
                                                const float4* __restrict__ knb4,
                                                const float4* __restrict__ root4,
                                                const float* __restrict__ bias,
                                                const float* __restrict__ dw,
                                                const float* __restrict__ db,
                                                float* __restrict__ H,
                                                float* __restrict__ util,
                                                int mode) {
    __shared__ unsigned int WsB[320 * 16];  // bf16-packed W': 20,480 B
    __shared__ float Gt[320 * 33];          // transposed Gext: 42,240 B
    __shared__ float4 parts[4 * 256];       // 16,384 B
    int t = threadIdx.x;
    int nb = blockIdx.x * 32;

    // stage W' = [knw | knb | root] verbatim, packed to bf16 pairs along o.
    {
#pragma unroll
        for (int c = 0; c < 10; ++c) {
            int idx = c * 256 + t;
            float4 v;
            if (idx < 2048) v = knw4[idx];
            else if (idx < 2304) v = knb4[idx - 2048];
            else v = root4[idx - 2304];
            int k = idx >> 3, o4 = idx & 7;
            WsB[k * 16 + o4 * 2 + 0] = f2bf(v.x) | (f2bf(v.y) << 16);
            WsB[k * 16 + o4 * 2 + 1] = f2bf(v.z) | (f2bf(v.w) << 16);
        }
    }
    // stage Gext coalesced (row-major reads), transposed into Gt[k][n]
    {
#pragma unroll
        for (int c = 0; c < 10; ++c) {
            int idx = c * 256 + t;          // 0..2559 = 32 nodes x 80 f4
            int n = idx / 80, k4 = idx % 80;
            float4 v;
            if (k4 < 72) v = G4[(size_t)(nb + n) * 72 + k4];
            else         v = X4[(size_t)(nb + n) * 8 + (k4 - 72)];
            int kr = k4 * 4;
            Gt[(kr + 0) * 33 + n] = v.x;
            Gt[(kr + 1) * 33 + n] = v.y;
            Gt[(kr + 2) * 33 + n] = v.z;
            Gt[(kr + 3) * 33 + n] = v.w;
        }
    }
    __syncthreads();

    int ks = t >> 6;           // wave = K slice (0..3)
    int lane = t & 63;
    int mg = lane >> 3;        // node group (0..7) -> local nodes mg*4..mg*4+3
    int jg = lane & 7;         // output quad
    int n0 = mg * 4;

    float4 z = make_float4(0.f, 0.f, 0.f, 0.f);
    float4 a0 = z, a1 = z, a2 = z, a3 = z;

    for (int r = 0; r < 20; ++r) {
        int k4 = ks * 20 + r;  // wave-uniform
#pragma unroll
        for (int kk = 0; kk < 4; ++kk) {
            int kr = (k4 * 4 + kk);
            uint2 wq = *(const uint2*)&WsB[kr * 16 + jg * 2];
            float4 w;
            w.x = bf2f(wq.x & 0xffffu); w.y = bf2f(wq.x >> 16);
            w.z = bf2f(wq.y & 0xffffu); w.w = bf2f(wq.y >> 16);
            const float* gr = &Gt[kr * 33 + n0];
            a0 = f4fma(gr[0], w, a0);
            a1 = f4fma(gr[1], w, a1);
            a2 = f4fma(gr[2], w, a2);
            a3 = f4fma(gr[3], w, a3);
        }
    }

    // deposit partials: parts[ks*256 + nl*8 + jg], nl = mg*4+m
    {
        int pb = ks * 256 + (mg * 4) * 8 + jg;
        parts[pb + 0 * 8] = a0;
        parts[pb + 1 * 8] = a1;
        parts[pb + 2 * 8] = a2;
        parts[pb + 3 * 8] = a3;
    }
    __syncthreads();

    // reduce: thread u -> (nl = u>>3, jr = u&7)
    int nl = t >> 3, jr = t & 7;
    float4 s0 = parts[0 * 256 + t];
    float4 s1 = parts[1 * 256 + t];
    float4 s2 = parts[2 * 256 + t];
    float4 s3 = parts[3 * 256 + t];
    float4 a;
    a.x = (s0.x + s1.x) + (s2.x + s3.x);
    a.y = (s0.y + s1.y) + (s2.y + s3.y);
    a.z = (s0.z + s1.z) + (s2.z + s3.z);
    a.w = (s0.w + s1.w) + (s2.w + s3.w);

    int n = nb + nl;
    float4 b = ((const float4*)bias)[jr];
    if (mode == 0) {
        float4 v;
        v.x = fmaxf(a.x + b.x, 0.f); v.y = fmaxf(a.y + b.y, 0.f);
        v.z = fmaxf(a.z + b.z, 0.f); v.w = fmaxf(a.w + b.w, 0.f);
        ((float4*)H)[n * 8 + jr] = v;
    } else {
        float4 dv = ((const float4*)dw)[jr];
        float p = fmaxf(a.x + b.x, 0.f) * dv.x + fmaxf(a.y + b.y, 0.f) * dv.y
                + fmaxf(a.z + b.z, 0.f) * dv.z + fmaxf(a.w + b.w, 0.f) * dv.w;
        p += __shfl_xor(p, 1);
        p += __shfl_xor(p, 2);
        p += __shfl_xor(p, 4);
        if (jr == 0) util[n] = p + db[0];
    }
}

// out[p] = util[idx_b[p]] - util[idx_a[p]]
__global__ void pair_kernel(const float* __restrict__ util, const int* __restrict__ ia,
                            const int* __restrict__ ib, float* __restrict__ out) {
    int p = blockIdx.x * blockDim.x + threadIdx.x;
    if (p >= N_PAIRS) return;
    out[p] = util[ib[p]] - util[ia[p]];
}

extern "C" void kernel_launch(void* const* d_in, const int* in_sizes, int n_in,
                              void* d_out, int out_size, void* d_ws, size_t ws_size,
                              hipStream_t stream) {
    const float* x     = (const float*)d_in[0];
    const float* e     = (const float*)d_in[1];
    const float* knw1  = (const float*)d_in[2];
    const float* knb1  = (const float*)d_in[3];
    const float* root1 = (const float*)d_in[4];
    const float* bias1 = (const float*)d_in[5];
    const float* knw2  = (const float*)d_in[6];
    const float* knb2  = (const float*)d_in[7];
    const float* root2 = (const float*)d_in[8];
    const float* bias2 = (const float*)d_in[9];
    const float* dw    = (const float*)d_in[10];
    const float* db    = (const float*)d_in[11];
    const int*   ei    = (const int*)d_in[12];
    const int*   ia    = (const int*)d_in[13];
    const int*   ib    = (const int*)d_in[14];
    float* out = (float*)d_out;

    float* ws = (float*)d_ws;
    float* G      = ws;                       // 20000*288 = 5,760,000 floats
    float* H      = ws + 5760000;             // 640,000
    float* util   = ws + 6400000;             // 20,000
    int*   cnt    = (int*)(ws + 6420000);     // 20,000
    int*   adjsrc = (int*)(ws + 6440000);     // 640,000 ints
    uint4* adjEb  = (uint4*)(ws + 7080000);   // 640,000 uint4 (16B-aligned)

    int nblk_epi = N_NODES / 32;                     // 625 (exact)
    int nblk_gat = (N_NODES * 64) / 256;             // 5000

    // ---- adjacency ----
    zero_cnt<<<(N_NODES + 255) / 256, 256, 0, stream>>>(cnt);
    fill_adj<<<(N_EDGES + 255) / 256, 256, 0, stream>>>(ei, e, cnt, adjsrc, adjEb);

    // ---- layer 1 ----
    edge_gather<<<nblk_gat, 256, 0, stream>>>(x, cnt, adjsrc, adjEb, G);
    epi_gemm<<<nblk_epi, 256, 0, stream>>>((const float4*)G, (const float4*)x,
                                           (const float4*)knw1, (const float4*)knb1,
                                           (const float4*)root1, bias1, dw, db,
                                           H, util, 0);
    // ---- layer 2 (+ readout) ----
    edge_gather<<<nblk_gat, 256, 0, stream>>>(H, cnt, adjsrc, adjEb, G);
    epi_gemm<<<nblk_epi, 256, 0, stream>>>((const float4*)G, (const float4*)H,
                                           (const float4*)knw2, (const float4*)knb2,
                                           (const float4*)root2, bias2, dw, db,
                                           H, util, 1);

    // ---- pairs ----
    pair_kernel<<<(N_PAIRS + 255) / 256, 256, 0, stream>>>(util, ia, ib, out);
}

// Round 28
// 68.734 us; speedup vs baseline: 1.3944x; 1.3944x over previous
//
#include <hip/hip_runtime.h>

#define N_NODES 20000
#define N_EDGES 160000
#define N_PAIRS 50000
#define DMAX 32
// F_IN = CHANNELS = 32, EDGE_DIM = 8; G row = 288 floats (knw 256 + knb 32)

typedef __attribute__((ext_vector_type(8))) short short8v;
typedef __attribute__((ext_vector_type(4))) float f32x4;

__device__ __forceinline__ float bf2f(unsigned int u) {  // low 16 bits = bf16
    return __uint_as_float(u << 16);
}
__device__ __forceinline__ unsigned int f2bf(float f) {  // RNE, low 16 bits
    unsigned int u = __float_as_uint(f);
    u += 0x7fffu + ((u >> 16) & 1u);
    return u >> 16;
}

// prep: zero cnt (blocks 0..78) + build MFMA B-fragment-ordered bf16 copies of
// W' = [knw|knb|root] for both layers (blocks 79..158).
// Wfrag[((nt*10+ks)*64 + l)*8 + e] = W'[k][o], k = ks*32+(l>>4)*8+e, o = nt*16+(l&15)
__global__ __launch_bounds__(256) void prep_kernel(int* __restrict__ cnt,
        const float* __restrict__ knw1, const float* __restrict__ knb1,
        const float* __restrict__ root1, ushort* __restrict__ wf1,
        const float* __restrict__ knw2, const float* __restrict__ knb2,
        const float* __restrict__ root2, ushort* __restrict__ wf2) {
    int b = blockIdx.x, t = threadIdx.x;
    if (b < 79) {
        int idx = b * 256 + t;
        if (idx < N_NODES) cnt[idx] = 0;
        return;
    }
    int u = (b - 79) * 256 + t;  // 0..20479
    const float *knw, *knb, *root;
    ushort* wf;
    if (u < 10240) { knw = knw1; knb = knb1; root = root1; wf = wf1; }
    else { u -= 10240; knw = knw2; knb = knb2; root = root2; wf = wf2; }
    int e = u & 7, l = (u >> 3) & 63, rest = u >> 9;
    int ks = rest % 10, nt = rest / 10;
    int k = ks * 32 + ((l >> 4) << 3) + e;
    int o = nt * 16 + (l & 15);
    float v;
    if (k < 256) v = knw[k * 32 + o];
    else if (k < 288) v = knb[(k - 256) * 32 + o];
    else v = root[(k - 288) * 32 + o];
    wf[u] = (ushort)f2bf(v);  // note: u re-offset == ((nt*10+ks)*64+l)*8+e
}

// adjacency by target: slot -> src (int) + bf16-packed E row (uint4, 16B).
__global__ __launch_bounds__(256) void fill_adj(const int* __restrict__ ei,
                                                const float* __restrict__ E,
                                                int* __restrict__ cnt,
                                                int* __restrict__ adjsrc,
                                                uint4* __restrict__ adjEb) {
    int e = blockIdx.x * blockDim.x + threadIdx.x;
    if (e >= N_EDGES) return;
    int2 st = ((const int2*)ei)[e];  // x = src, y = tgt
    int slot = atomicAdd(&cnt[st.y], 1);
    if (slot < DMAX) {
        int idx = (st.y << 5) + slot;
        adjsrc[idx] = st.x;
        const float4* e4 = (const float4*)(E + (size_t)e * 8);
        float4 a = e4[0], b = e4[1];
        uint4 p;
        p.x = f2bf(a.x) | (f2bf(a.y) << 16);
        p.y = f2bf(a.z) | (f2bf(a.w) << 16);
        p.z = f2bf(b.x) | (f2bf(b.y) << 16);
        p.w = f2bf(b.z) | (f2bf(b.w) << 16);
        adjEb[idx] = p;
    }
}

#define EDGE_FMA_P(p, xv)                                                      \
    g0 += bf2f((p).x & 0xffffu) * (xv); g1 += bf2f((p).x >> 16) * (xv);        \
    g2 += bf2f((p).y & 0xffffu) * (xv); g3 += bf2f((p).y >> 16) * (xv);        \
    g4 += bf2f((p).z & 0xffffu) * (xv); g5 += bf2f((p).z >> 16) * (xv);        \
    g6 += bf2f((p).w & 0xffffu) * (xv); g7 += bf2f((p).w >> 16) * (xv);        \
    g8 += (xv);

// G gather (R14/R18-validated): ONE WAVE PER NODE; chunks of 8 edges (4 per
// half), independent slot/E/X loads issued before FMAs.
__global__ __launch_bounds__(256) void edge_gather(const float* __restrict__ X,
                                                   const int* __restrict__ cnt,
                                                   const int* __restrict__ adjsrc,
                                                   const uint4* __restrict__ adjEb,
                                                   float* __restrict__ G) {
    int t = blockIdx.x * blockDim.x + threadIdx.x;
    int n = t >> 6;
    if (n >= N_NODES) return;
    int lane = t & 63;
    int i = lane & 31;
    int half = lane >> 5;

    int deg = min(cnt[n], DMAX);
    int base = n << 5;
    float g0 = 0.f, g1 = 0.f, g2 = 0.f, g3 = 0.f;
    float g4 = 0.f, g5 = 0.f, g6 = 0.f, g7 = 0.f, g8 = 0.f;

    int c = 0;
    for (; c + 8 <= deg; c += 8) {
        int k0 = base + c + half * 4;
        int s0 = adjsrc[k0 + 0];
        int s1 = adjsrc[k0 + 1];
        int s2 = adjsrc[k0 + 2];
        int s3 = adjsrc[k0 + 3];
        uint4 p0 = adjEb[k0 + 0];
        uint4 p1 = adjEb[k0 + 1];
        uint4 p2 = adjEb[k0 + 2];
        uint4 p3 = adjEb[k0 + 3];
        float xv0 = X[s0 * 32 + i];
        float xv1 = X[s1 * 32 + i];
        float xv2 = X[s2 * 32 + i];
        float xv3 = X[s3 * 32 + i];
        EDGE_FMA_P(p0, xv0);
        EDGE_FMA_P(p1, xv1);
        EDGE_FMA_P(p2, xv2);
        EDGE_FMA_P(p3, xv3);
    }
    for (int k = c + half; k < deg; k += 2) {
        int s = adjsrc[base + k];
        uint4 p = adjEb[base + k];
        float xv = X[s * 32 + i];
        EDGE_FMA_P(p, xv);
    }

    g0 += __shfl_xor(g0, 32); g1 += __shfl_xor(g1, 32);
    g2 += __shfl_xor(g2, 32); g3 += __shfl_xor(g3, 32);
    g4 += __shfl_xor(g4, 32); g5 += __shfl_xor(g5, 32);
    g6 += __shfl_xor(g6, 32); g7 += __shfl_xor(g7, 32);
    g8 += __shfl_xor(g8, 32);

    if (half == 0) {
        float* gr = G + (size_t)n * 288;
        gr[0 * 32 + i] = g0; gr[1 * 32 + i] = g1;
        gr[2 * 32 + i] = g2; gr[3 * 32 + i] = g3;
        gr[4 * 32 + i] = g4; gr[5 * 32 + i] = g5;
        gr[6 * 32 + i] = g6; gr[7 * 32 + i] = g7;
        gr[256 + i] = g8;
    }
}

// Epilogue via MFMA (R27): out[16-node tile][32 outs] = Gext @ W' in bf16.
//   A (16x32 k-slice): lane l -> row = l&15, k = (l>>4)*8 + e (fp32 G/X,
//   packed to bf16 in-reg). B from Wfrag (fragment-ordered, L2-hot,
//   lane-contiguous 16B). C (verified m89): col = l&15, row = (l>>4)*4 + v.
// 1250 tiles = 313 blocks x 4 waves (tail waves early-exit; no LDS/barriers).
// mode 0: H[n][o] = relu(out + bias[o]);  mode 1: util[n] = db + relu(.)@dw
__global__ __launch_bounds__(256) void epi_mfma(const float* __restrict__ G,
                                                const float* __restrict__ X,
                                                const ushort* __restrict__ wfrag,
                                                const float* __restrict__ bias,
                                                const float* __restrict__ dw,
                                                const float* __restrict__ db,
                                                float* __restrict__ H,
                                                float* __restrict__ util,
                                                int mode) {
    int wv = threadIdx.x >> 6;
    int tile = blockIdx.x * 4 + wv;
    if (tile >= N_NODES / 16) return;
    int l = threadIdx.x & 63;
    int row = l & 15, kg = l >> 4;
    int node = tile * 16 + row;

    f32x4 acc0 = {0.f, 0.f, 0.f, 0.f};
    f32x4 acc1 = {0.f, 0.f, 0.f, 0.f};
    const float* gbase = G + (size_t)node * 288 + kg * 8;
    const float* xbase = X + (size_t)node * 32 + kg * 8;

#pragma unroll
    for (int ks = 0; ks < 10; ++ks) {
        const float* src = (ks < 9) ? (gbase + ks * 32) : xbase;
        float4 f0 = *(const float4*)(src);
        float4 f1 = *(const float4*)(src + 4);
        short8v a;
        a[0] = (short)f2bf(f0.x); a[1] = (short)f2bf(f0.y);
        a[2] = (short)f2bf(f0.z); a[3] = (short)f2bf(f0.w);
        a[4] = (short)f2bf(f1.x); a[5] = (short)f2bf(f1.y);
        a[6] = (short)f2bf(f1.z); a[7] = (short)f2bf(f1.w);
        short8v b0 = *(const short8v*)(wfrag + ((0 * 10 + ks) * 64 + l) * 8);
        short8v b1 = *(const short8v*)(wfrag + ((1 * 10 + ks) * 64 + l) * 8);
        acc0 = __builtin_amdgcn_mfma_f32_16x16x32_bf16(a, b0, acc0, 0, 0, 0);
        acc1 = __builtin_amdgcn_mfma_f32_16x16x32_bf16(a, b1, acc1, 0, 0, 0);
    }

    int o0 = l & 15, o1 = 16 + (l & 15);
    int rbase = tile * 16 + kg * 4;
    if (mode == 0) {
#pragma unroll
        for (int v = 0; v < 4; ++v) {
            int n = rbase + v;
            H[n * 32 + o0] = fmaxf(acc0[v] + bias[o0], 0.f);
            H[n * 32 + o1] = fmaxf(acc1[v] + bias[o1], 0.f);
        }
    } else {
        float b0v = bias[o0], b1v = bias[o1];
        float d0 = dw[o0], d1 = dw[o1];
        float dbv = db[0];
#pragma unroll
        for (int v = 0; v < 4; ++v) {
            float p = fmaxf(acc0[v] + b0v, 0.f) * d0
                    + fmaxf(acc1[v] + b1v, 0.f) * d1;
            p += __shfl_xor(p, 1);
            p += __shfl_xor(p, 2);
            p += __shfl_xor(p, 4);
            p += __shfl_xor(p, 8);
            if ((l & 15) == 0) util[rbase + v] = p + dbv;
        }
    }
}

// out[p] = util[idx_b[p]] - util[idx_a[p]]
__global__ void pair_kernel(const float* __restrict__ util, const int* __restrict__ ia,
                            const int* __restrict__ ib, float* __restrict__ out) {
    int p = blockIdx.x * blockDim.x + threadIdx.x;
    if (p >= N_PAIRS) return;
    out[p] = util[ib[p]] - util[ia[p]];
}

extern "C" void kernel_launch(void* const* d_in, const int* in_sizes, int n_in,
                              void* d_out, int out_size, void* d_ws, size_t ws_size,
                              hipStream_t stream) {
    const float* x     = (const float*)d_in[0];
    const float* e     = (const float*)d_in[1];
    const float* knw1  = (const float*)d_in[2];
    const float* knb1  = (const float*)d_in[3];
    const float* root1 = (const float*)d_in[4];
    const float* bias1 = (const float*)d_in[5];
    const float* knw2  = (const float*)d_in[6];
    const float* knb2  = (const float*)d_in[7];
    const float* root2 = (const float*)d_in[8];
    const float* bias2 = (const float*)d_in[9];
    const float* dw    = (const float*)d_in[10];
    const float* db    = (const float*)d_in[11];
    const int*   ei    = (const int*)d_in[12];
    const int*   ia    = (const int*)d_in[13];
    const int*   ib    = (const int*)d_in[14];
    float* out = (float*)d_out;

    float* ws = (float*)d_ws;
    float*  G      = ws;                        // 20000*288 = 5,760,000 floats
    float*  H      = ws + 5760000;              // 640,000
    float*  util   = ws + 6400000;              // 20,000
    int*    cnt    = (int*)(ws + 6420000);      // 20,000
    int*    adjsrc = (int*)(ws + 6440000);      // 640,000 ints
    uint4*  adjEb  = (uint4*)(ws + 7080000);    // 640,000 uint4 -> ends 9,640,000
    ushort* wf1    = (ushort*)(ws + 9640000);   // 10,240 ushorts (16B-aligned)
    ushort* wf2    = (ushort*)(ws + 9645120);   // 10,240 ushorts (16B-aligned)

    int nblk_epi = (N_NODES / 16 + 3) / 4;           // 313
    int nblk_gat = (N_NODES * 64) / 256;             // 5000

    // ---- prep: zero cnt + build both Wfrag copies ----
    prep_kernel<<<159, 256, 0, stream>>>(cnt, knw1, knb1, root1, wf1,
                                         knw2, knb2, root2, wf2);
    fill_adj<<<(N_EDGES + 255) / 256, 256, 0, stream>>>(ei, e, cnt, adjsrc, adjEb);

    // ---- layer 1 ----
    edge_gather<<<nblk_gat, 256, 0, stream>>>(x, cnt, adjsrc, adjEb, G);
    epi_mfma<<<nblk_epi, 256, 0, stream>>>(G, x, wf1, bias1, dw, db, H, util, 0);

    // ---- layer 2 (+ readout) ----
    edge_gather<<<nblk_gat, 256, 0, stream>>>(H, cnt, adjsrc, adjEb, G);
    epi_mfma<<<nblk_epi, 256, 0, stream>>>(G, H, wf2, bias2, dw, db, H, util, 1);

    // ---- pairs ----
    pair_kernel<<<(N_PAIRS + 255) / 256, 256, 0, stream>>>(util, ia, ib, out);
}

// Round 29
// 59.660 us; speedup vs baseline: 1.6065x; 1.1521x over previous
//
#include <hip/hip_runtime.h>

#define N_NODES 20000
#define N_EDGES 160000
#define N_PAIRS 50000
#define DMAX 32
// F_IN = CHANNELS = 32, EDGE_DIM = 8
// Gb = bf16 A-fragment buffer: [tile][ks=0..9][l=0..63][e=0..7] ushorts.
//   value G[n][k]: tile=n>>4, row=n&15; ks=k>>5, l=((k&31)>>3)*16+row, e=k&7
//   ks 0..7 = knw-G, ks 8 = knb-sum, ks 9 = root (X row).

typedef __attribute__((ext_vector_type(8))) short short8v;
typedef __attribute__((ext_vector_type(4))) float f32x4;

__device__ __forceinline__ float bf2f(unsigned int u) {  // low 16 bits = bf16
    return __uint_as_float(u << 16);
}
__device__ __forceinline__ unsigned int f2bf(float f) {  // RNE, low 16 bits
    unsigned int u = __float_as_uint(f);
    u += 0x7fffu + ((u >> 16) & 1u);
    return u >> 16;
}

// prep: zero cnt (blocks 0..78) + build MFMA B-fragment bf16 copies of
// W' = [knw|knb|root] for both layers (blocks 79..158).
// Wfrag[((nt*10+ks)*64 + l)*8 + e] = W'[k][o], k = ks*32+(l>>4)*8+e, o = nt*16+(l&15)
__global__ __launch_bounds__(256) void prep_kernel(int* __restrict__ cnt,
        const float* __restrict__ knw1, const float* __restrict__ knb1,
        const float* __restrict__ root1, ushort* __restrict__ wf1,
        const float* __restrict__ knw2, const float* __restrict__ knb2,
        const float* __restrict__ root2, ushort* __restrict__ wf2) {
    int b = blockIdx.x, t = threadIdx.x;
    if (b < 79) {
        int idx = b * 256 + t;
        if (idx < N_NODES) cnt[idx] = 0;
        return;
    }
    int u = (b - 79) * 256 + t;  // 0..20479
    const float *knw, *knb, *root;
    ushort* wf;
    if (u < 10240) { knw = knw1; knb = knb1; root = root1; wf = wf1; }
    else { u -= 10240; knw = knw2; knb = knb2; root = root2; wf = wf2; }
    int e = u & 7, l = (u >> 3) & 63, rest = u >> 9;
    int ks = rest % 10, nt = rest / 10;
    int k = ks * 32 + ((l >> 4) << 3) + e;
    int o = nt * 16 + (l & 15);
    float v;
    if (k < 256) v = knw[k * 32 + o];
    else if (k < 288) v = knb[(k - 256) * 32 + o];
    else v = root[(k - 288) * 32 + o];
    wf[u] = (ushort)f2bf(v);
}

// adjacency by target: slot -> src (int) + bf16-packed E row (uint4, 16B).
__global__ __launch_bounds__(256) void fill_adj(const int* __restrict__ ei,
                                                const float* __restrict__ E,
                                                int* __restrict__ cnt,
                                                int* __restrict__ adjsrc,
                                                uint4* __restrict__ adjEb) {
    int e = blockIdx.x * blockDim.x + threadIdx.x;
    if (e >= N_EDGES) return;
    int2 st = ((const int2*)ei)[e];  // x = src, y = tgt
    int slot = atomicAdd(&cnt[st.y], 1);
    if (slot < DMAX) {
        int idx = (st.y << 5) + slot;
        adjsrc[idx] = st.x;
        const float4* e4 = (const float4*)(E + (size_t)e * 8);
        float4 a = e4[0], b = e4[1];
        uint4 p;
        p.x = f2bf(a.x) | (f2bf(a.y) << 16);
        p.y = f2bf(a.z) | (f2bf(a.w) << 16);
        p.z = f2bf(b.x) | (f2bf(b.y) << 16);
        p.w = f2bf(b.z) | (f2bf(b.w) << 16);
        adjEb[idx] = p;
    }
}

#define EDGE_FMA_P(p, xv)                                                      \
    g0 += bf2f((p).x & 0xffffu) * (xv); g1 += bf2f((p).x >> 16) * (xv);        \
    g2 += bf2f((p).y & 0xffffu) * (xv); g3 += bf2f((p).y >> 16) * (xv);        \
    g4 += bf2f((p).z & 0xffffu) * (xv); g5 += bf2f((p).z >> 16) * (xv);        \
    g6 += bf2f((p).w & 0xffffu) * (xv); g7 += bf2f((p).w >> 16) * (xv);        \
    g8 += (xv);

// G gather (R14/R18-validated core): ONE WAVE PER NODE; chunks of 8 edges
// (4 per half), independent slot/E/X loads issued before FMAs. Epilogue now
// stores bf16 A-fragments to Gb (incl. ks=9 root block from X).
__global__ __launch_bounds__(256) void edge_gather(const float* __restrict__ X,
                                                   const int* __restrict__ cnt,
                                                   const int* __restrict__ adjsrc,
                                                   const uint4* __restrict__ adjEb,
                                                   ushort* __restrict__ Gb) {
    int t = blockIdx.x * blockDim.x + threadIdx.x;
    int n = t >> 6;
    if (n >= N_NODES) return;
    int lane = t & 63;
    int i = lane & 31;
    int half = lane >> 5;

    int deg = min(cnt[n], DMAX);
    int base = n << 5;
    float g0 = 0.f, g1 = 0.f, g2 = 0.f, g3 = 0.f;
    float g4 = 0.f, g5 = 0.f, g6 = 0.f, g7 = 0.f, g8 = 0.f;

    int c = 0;
    for (; c + 8 <= deg; c += 8) {
        int k0 = base + c + half * 4;
        int s0 = adjsrc[k0 + 0];
        int s1 = adjsrc[k0 + 1];
        int s2 = adjsrc[k0 + 2];
        int s3 = adjsrc[k0 + 3];
        uint4 p0 = adjEb[k0 + 0];
        uint4 p1 = adjEb[k0 + 1];
        uint4 p2 = adjEb[k0 + 2];
        uint4 p3 = adjEb[k0 + 3];
        float xv0 = X[s0 * 32 + i];
        float xv1 = X[s1 * 32 + i];
        float xv2 = X[s2 * 32 + i];
        float xv3 = X[s3 * 32 + i];
        EDGE_FMA_P(p0, xv0);
        EDGE_FMA_P(p1, xv1);
        EDGE_FMA_P(p2, xv2);
        EDGE_FMA_P(p3, xv3);
    }
    for (int k = c + half; k < deg; k += 2) {
        int s = adjsrc[base + k];
        uint4 p = adjEb[base + k];
        float xv = X[s * 32 + i];
        EDGE_FMA_P(p, xv);
    }

    g0 += __shfl_xor(g0, 32); g1 += __shfl_xor(g1, 32);
    g2 += __shfl_xor(g2, 32); g3 += __shfl_xor(g3, 32);
    g4 += __shfl_xor(g4, 32); g5 += __shfl_xor(g5, 32);
    g6 += __shfl_xor(g6, 32); g7 += __shfl_xor(g7, 32);
    g8 += __shfl_xor(g8, 32);

    if (half == 0) {
        float xself = X[n * 32 + i];
        // fragment store: ks block = 512 ushorts; off covers 4x16B chunks
        size_t tb = (size_t)(n >> 4) * 10 * 512;
        int off = (((i >> 3) << 4) | (n & 15)) * 8 + (i & 7);
        Gb[tb + 0 * 512 + off] = (ushort)f2bf(g0);
        Gb[tb + 1 * 512 + off] = (ushort)f2bf(g1);
        Gb[tb + 2 * 512 + off] = (ushort)f2bf(g2);
        Gb[tb + 3 * 512 + off] = (ushort)f2bf(g3);
        Gb[tb + 4 * 512 + off] = (ushort)f2bf(g4);
        Gb[tb + 5 * 512 + off] = (ushort)f2bf(g5);
        Gb[tb + 6 * 512 + off] = (ushort)f2bf(g6);
        Gb[tb + 7 * 512 + off] = (ushort)f2bf(g7);
        Gb[tb + 8 * 512 + off] = (ushort)f2bf(g8);
        Gb[tb + 9 * 512 + off] = (ushort)f2bf(xself);
    }
}

// Epilogue via MFMA (R28): A from Gb (fragment-ordered bf16, wave reads 1KB
// LINEAR per kstep), B from Wfrag (L2-hot). C layout (verified m89):
// col = l&15, row = (l>>4)*4 + v. 1250 tiles = 313 blocks x 4 waves.
// mode 0: H[n][o] = relu(out + bias[o]);  mode 1: util[n] = db + relu(.)@dw
__global__ __launch_bounds__(256) void epi_mfma(const ushort* __restrict__ Gb,
                                                const ushort* __restrict__ wfrag,
                                                const float* __restrict__ bias,
                                                const float* __restrict__ dw,
                                                const float* __restrict__ db,
                                                float* __restrict__ H,
                                                float* __restrict__ util,
                                                int mode) {
    int wv = threadIdx.x >> 6;
    int tile = blockIdx.x * 4 + wv;
    if (tile >= N_NODES / 16) return;
    int l = threadIdx.x & 63;
    int kg = l >> 4;

    f32x4 acc0 = {0.f, 0.f, 0.f, 0.f};
    f32x4 acc1 = {0.f, 0.f, 0.f, 0.f};
    const ushort* gb = Gb + ((size_t)tile * 10 * 64 + l) * 8;

#pragma unroll
    for (int ks = 0; ks < 10; ++ks) {
        short8v a = *(const short8v*)(gb + ks * 512);
        short8v b0 = *(const short8v*)(wfrag + ((0 * 10 + ks) * 64 + l) * 8);
        short8v b1 = *(const short8v*)(wfrag + ((1 * 10 + ks) * 64 + l) * 8);
        acc0 = __builtin_amdgcn_mfma_f32_16x16x32_bf16(a, b0, acc0, 0, 0, 0);
        acc1 = __builtin_amdgcn_mfma_f32_16x16x32_bf16(a, b1, acc1, 0, 0, 0);
    }

    int o0 = l & 15, o1 = 16 + (l & 15);
    int rbase = tile * 16 + kg * 4;
    if (mode == 0) {
#pragma unroll
        for (int v = 0; v < 4; ++v) {
            int n = rbase + v;
            H[n * 32 + o0] = fmaxf(acc0[v] + bias[o0], 0.f);
            H[n * 32 + o1] = fmaxf(acc1[v] + bias[o1], 0.f);
        }
    } else {
        float b0v = bias[o0], b1v = bias[o1];
        float d0 = dw[o0], d1 = dw[o1];
        float dbv = db[0];
#pragma unroll
        for (int v = 0; v < 4; ++v) {
            float p = fmaxf(acc0[v] + b0v, 0.f) * d0
                    + fmaxf(acc1[v] + b1v, 0.f) * d1;
            p += __shfl_xor(p, 1);
            p += __shfl_xor(p, 2);
            p += __shfl_xor(p, 4);
            p += __shfl_xor(p, 8);
            if ((l & 15) == 0) util[rbase + v] = p + dbv;
        }
    }
}

// out[p] = util[idx_b[p]] - util[idx_a[p]]
__global__ void pair_kernel(const float* __restrict__ util, const int* __restrict__ ia,
                            const int* __restrict__ ib, float* __restrict__ out) {
    int p = blockIdx.x * blockDim.x + threadIdx.x;
    if (p >= N_PAIRS) return;
    out[p] = util[ib[p]] - util[ia[p]];
}

extern "C" void kernel_launch(void* const* d_in, const int* in_sizes, int n_in,
                              void* d_out, int out_size, void* d_ws, size_t ws_size,
                              hipStream_t stream) {
    const float* x     = (const float*)d_in[0];
    const float* e     = (const float*)d_in[1];
    const float* knw1  = (const float*)d_in[2];
    const float* knb1  = (const float*)d_in[3];
    const float* root1 = (const float*)d_in[4];
    const float* bias1 = (const float*)d_in[5];
    const float* knw2  = (const float*)d_in[6];
    const float* knb2  = (const float*)d_in[7];
    const float* root2 = (const float*)d_in[8];
    const float* bias2 = (const float*)d_in[9];
    const float* dw    = (const float*)d_in[10];
    const float* db    = (const float*)d_in[11];
    const int*   ei    = (const int*)d_in[12];
    const int*   ia    = (const int*)d_in[13];
    const int*   ib    = (const int*)d_in[14];
    float* out = (float*)d_out;

    float* ws = (float*)d_ws;
    ushort* Gb     = (ushort*)ws;               // 1250*10*512 = 6,400,000 ushorts
    float*  H      = ws + 3200000;              // 640,000 floats
    float*  util   = ws + 3840000;              // 20,000
    int*    cnt    = (int*)(ws + 3860000);      // 20,000
    int*    adjsrc = (int*)(ws + 3880000);      // 640,000 ints
    uint4*  adjEb  = (uint4*)(ws + 4520000);    // 640,000 uint4 -> ends 7,080,000
    ushort* wf1    = (ushort*)(ws + 7080000);   // 20,480 ushorts
    ushort* wf2    = (ushort*)(ws + 7085120);   // 20,480 ushorts

    int nblk_epi = (N_NODES / 16 + 3) / 4;           // 313
    int nblk_gat = (N_NODES * 64) / 256;             // 5000

    // ---- prep: zero cnt + build both Wfrag copies ----
    prep_kernel<<<159, 256, 0, stream>>>(cnt, knw1, knb1, root1, wf1,
                                         knw2, knb2, root2, wf2);
    fill_adj<<<(N_EDGES + 255) / 256, 256, 0, stream>>>(ei, e, cnt, adjsrc, adjEb);

    // ---- layer 1 ----
    edge_gather<<<nblk_gat, 256, 0, stream>>>(x, cnt, adjsrc, adjEb, Gb);
    epi_mfma<<<nblk_epi, 256, 0, stream>>>(Gb, wf1, bias1, dw, db, H, util, 0);

    // ---- layer 2 (+ readout) ----
    edge_gather<<<nblk_gat, 256, 0, stream>>>(H, cnt, adjsrc, adjEb, Gb);
    epi_mfma<<<nblk_epi, 256, 0, stream>>>(Gb, wf2, bias2, dw, db, H, util, 1);

    // ---- pairs ----
    pair_kernel<<<(N_PAIRS + 255) / 256, 256, 0, stream>>>(util, ia, ib, out);
}

// Round 30
// 59.265 us; speedup vs baseline: 1.6172x; 1.0067x over previous
//
#include <hip/hip_runtime.h>

#define N_NODES 20000
#define N_EDGES 160000
#define N_PAIRS 50000
#define DMAX 32
// F_IN = CHANNELS = 32, EDGE_DIM = 8
// Gb = bf16 A-fragment buffer: [tile][ks=0..9][l=0..63][e=0..7] ushorts.
//   value G[n][k]: tile=n>>4, row=n&15; ks=k>>5, l=((k&31)>>3)*16+row, e=k&7
//   ks 0..7 = knw-G, ks 8 = knb-sum, ks 9 = root (X/H row).
// H stored bf16 (halves layer-2 random-gather footprint; L2-resident).

typedef __attribute__((ext_vector_type(8))) short short8v;
typedef __attribute__((ext_vector_type(4))) float f32x4;

__device__ __forceinline__ float bf2f(unsigned int u) {  // low 16 bits = bf16
    return __uint_as_float(u << 16);
}
__device__ __forceinline__ unsigned int f2bf(float f) {  // RNE, low 16 bits
    unsigned int u = __float_as_uint(f);
    u += 0x7fffu + ((u >> 16) & 1u);
    return u >> 16;
}

// prep: zero cnt (blocks 0..78) + build MFMA B-fragment bf16 copies of
// W' = [knw|knb|root] for both layers (blocks 79..158).
// Wfrag[((nt*10+ks)*64 + l)*8 + e] = W'[k][o], k = ks*32+(l>>4)*8+e, o = nt*16+(l&15)
__global__ __launch_bounds__(256) void prep_kernel(int* __restrict__ cnt,
        const float* __restrict__ knw1, const float* __restrict__ knb1,
        const float* __restrict__ root1, ushort* __restrict__ wf1,
        const float* __restrict__ knw2, const float* __restrict__ knb2,
        const float* __restrict__ root2, ushort* __restrict__ wf2) {
    int b = blockIdx.x, t = threadIdx.x;
    if (b < 79) {
        int idx = b * 256 + t;
        if (idx < N_NODES) cnt[idx] = 0;
        return;
    }
    int u = (b - 79) * 256 + t;  // 0..20479
    const float *knw, *knb, *root;
    ushort* wf;
    if (u < 10240) { knw = knw1; knb = knb1; root = root1; wf = wf1; }
    else { u -= 10240; knw = knw2; knb = knb2; root = root2; wf = wf2; }
    int e = u & 7, l = (u >> 3) & 63, rest = u >> 9;
    int ks = rest % 10, nt = rest / 10;
    int k = ks * 32 + ((l >> 4) << 3) + e;
    int o = nt * 16 + (l & 15);
    float v;
    if (k < 256) v = knw[k * 32 + o];
    else if (k < 288) v = knb[(k - 256) * 32 + o];
    else v = root[(k - 288) * 32 + o];
    wf[u] = (ushort)f2bf(v);
}

// adjacency by target: slot -> src (int) + bf16-packed E row (uint4, 16B).
__global__ __launch_bounds__(256) void fill_adj(const int* __restrict__ ei,
                                                const float* __restrict__ E,
                                                int* __restrict__ cnt,
                                                int* __restrict__ adjsrc,
                                                uint4* __restrict__ adjEb) {
    int e = blockIdx.x * blockDim.x + threadIdx.x;
    if (e >= N_EDGES) return;
    int2 st = ((const int2*)ei)[e];  // x = src, y = tgt
    int slot = atomicAdd(&cnt[st.y], 1);
    if (slot < DMAX) {
        int idx = (st.y << 5) + slot;
        adjsrc[idx] = st.x;
        const float4* e4 = (const float4*)(E + (size_t)e * 8);
        float4 a = e4[0], b = e4[1];
        uint4 p;
        p.x = f2bf(a.x) | (f2bf(a.y) << 16);
        p.y = f2bf(a.z) | (f2bf(a.w) << 16);
        p.z = f2bf(b.x) | (f2bf(b.y) << 16);
        p.w = f2bf(b.z) | (f2bf(b.w) << 16);
        adjEb[idx] = p;
    }
}

#define EDGE_FMA_P(p, xv)                                                      \
    g0 += bf2f((p).x & 0xffffu) * (xv); g1 += bf2f((p).x >> 16) * (xv);        \
    g2 += bf2f((p).y & 0xffffu) * (xv); g3 += bf2f((p).y >> 16) * (xv);        \
    g4 += bf2f((p).z & 0xffffu) * (xv); g5 += bf2f((p).z >> 16) * (xv);        \
    g6 += bf2f((p).w & 0xffffu) * (xv); g7 += bf2f((p).w >> 16) * (xv);        \
    g8 += (xv);

// G gather (R14/R18-validated core): ONE WAVE PER NODE; chunks of 8 edges
// (4 per half), independent slot/E/X loads issued before FMAs. Stores bf16
// A-fragments to Gb (incl. ks=9 root block). BF=0: fp32 X; BF=1: bf16 H.
template<int BF>
__global__ __launch_bounds__(256) void edge_gather_t(const float* __restrict__ Xf,
                                                     const ushort* __restrict__ Xh,
                                                     const int* __restrict__ cnt,
                                                     const int* __restrict__ adjsrc,
                                                     const uint4* __restrict__ adjEb,
                                                     ushort* __restrict__ Gb) {
    int t = blockIdx.x * blockDim.x + threadIdx.x;
    int n = t >> 6;
    if (n >= N_NODES) return;
    int lane = t & 63;
    int i = lane & 31;
    int half = lane >> 5;

    int deg = min(cnt[n], DMAX);
    int base = n << 5;
    float g0 = 0.f, g1 = 0.f, g2 = 0.f, g3 = 0.f;
    float g4 = 0.f, g5 = 0.f, g6 = 0.f, g7 = 0.f, g8 = 0.f;

    int c = 0;
    for (; c + 8 <= deg; c += 8) {
        int k0 = base + c + half * 4;
        int s0 = adjsrc[k0 + 0];
        int s1 = adjsrc[k0 + 1];
        int s2 = adjsrc[k0 + 2];
        int s3 = adjsrc[k0 + 3];
        uint4 p0 = adjEb[k0 + 0];
        uint4 p1 = adjEb[k0 + 1];
        uint4 p2 = adjEb[k0 + 2];
        uint4 p3 = adjEb[k0 + 3];
        float xv0, xv1, xv2, xv3;
        if (BF) {
            xv0 = bf2f(Xh[s0 * 32 + i]);
            xv1 = bf2f(Xh[s1 * 32 + i]);
            xv2 = bf2f(Xh[s2 * 32 + i]);
            xv3 = bf2f(Xh[s3 * 32 + i]);
        } else {
            xv0 = Xf[s0 * 32 + i];
            xv1 = Xf[s1 * 32 + i];
            xv2 = Xf[s2 * 32 + i];
            xv3 = Xf[s3 * 32 + i];
        }
        EDGE_FMA_P(p0, xv0);
        EDGE_FMA_P(p1, xv1);
        EDGE_FMA_P(p2, xv2);
        EDGE_FMA_P(p3, xv3);
    }
    for (int k = c + half; k < deg; k += 2) {
        int s = adjsrc[base + k];
        uint4 p = adjEb[base + k];
        float xv = BF ? bf2f(Xh[s * 32 + i]) : Xf[s * 32 + i];
        EDGE_FMA_P(p, xv);
    }

    g0 += __shfl_xor(g0, 32); g1 += __shfl_xor(g1, 32);
    g2 += __shfl_xor(g2, 32); g3 += __shfl_xor(g3, 32);
    g4 += __shfl_xor(g4, 32); g5 += __shfl_xor(g5, 32);
    g6 += __shfl_xor(g6, 32); g7 += __shfl_xor(g7, 32);
    g8 += __shfl_xor(g8, 32);

    if (half == 0) {
        float xself = BF ? bf2f(Xh[n * 32 + i]) : Xf[n * 32 + i];
        size_t tb = (size_t)(n >> 4) * 10 * 512;
        int off = (((i >> 3) << 4) | (n & 15)) * 8 + (i & 7);
        Gb[tb + 0 * 512 + off] = (ushort)f2bf(g0);
        Gb[tb + 1 * 512 + off] = (ushort)f2bf(g1);
        Gb[tb + 2 * 512 + off] = (ushort)f2bf(g2);
        Gb[tb + 3 * 512 + off] = (ushort)f2bf(g3);
        Gb[tb + 4 * 512 + off] = (ushort)f2bf(g4);
        Gb[tb + 5 * 512 + off] = (ushort)f2bf(g5);
        Gb[tb + 6 * 512 + off] = (ushort)f2bf(g6);
        Gb[tb + 7 * 512 + off] = (ushort)f2bf(g7);
        Gb[tb + 8 * 512 + off] = (ushort)f2bf(g8);
        Gb[tb + 9 * 512 + off] = (ushort)f2bf(xself);
    }
}

// Epilogue via MFMA (R28-validated): A from Gb (wave reads 1KB linear per
// kstep), B from Wfrag (L2-hot). C layout (verified m89): col=l&15,
// row=(l>>4)*4+v. 1250 tiles = 313 blocks x 4 waves.
// mode 0: H16[n][o] = bf16(relu(out + bias[o]));
// mode 1: util[n] = db + sum_o relu(out + bias[o]) * dw[o]
__global__ __launch_bounds__(256) void epi_mfma(const ushort* __restrict__ Gb,
                                                const ushort* __restrict__ wfrag,
                                                const float* __restrict__ bias,
                                                const float* __restrict__ dw,
                                                const float* __restrict__ db,
                                                ushort* __restrict__ H16,
                                                float* __restrict__ util,
                                                int mode) {
    int wv = threadIdx.x >> 6;
    int tile = blockIdx.x * 4 + wv;
    if (tile >= N_NODES / 16) return;
    int l = threadIdx.x & 63;
    int kg = l >> 4;

    f32x4 acc0 = {0.f, 0.f, 0.f, 0.f};
    f32x4 acc1 = {0.f, 0.f, 0.f, 0.f};
    const ushort* gb = Gb + ((size_t)tile * 10 * 64 + l) * 8;

#pragma unroll
    for (int ks = 0; ks < 10; ++ks) {
        short8v a = *(const short8v*)(gb + ks * 512);
        short8v b0 = *(const short8v*)(wfrag + ((0 * 10 + ks) * 64 + l) * 8);
        short8v b1 = *(const short8v*)(wfrag + ((1 * 10 + ks) * 64 + l) * 8);
        acc0 = __builtin_amdgcn_mfma_f32_16x16x32_bf16(a, b0, acc0, 0, 0, 0);
        acc1 = __builtin_amdgcn_mfma_f32_16x16x32_bf16(a, b1, acc1, 0, 0, 0);
    }

    int o0 = l & 15, o1 = 16 + (l & 15);
    int rbase = tile * 16 + kg * 4;
    if (mode == 0) {
#pragma unroll
        for (int v = 0; v < 4; ++v) {
            int n = rbase + v;
            H16[n * 32 + o0] = (ushort)f2bf(fmaxf(acc0[v] + bias[o0], 0.f));
            H16[n * 32 + o1] = (ushort)f2bf(fmaxf(acc1[v] + bias[o1], 0.f));
        }
    } else {
        float b0v = bias[o0], b1v = bias[o1];
        float d0 = dw[o0], d1 = dw[o1];
        float dbv = db[0];
#pragma unroll
        for (int v = 0; v < 4; ++v) {
            float p = fmaxf(acc0[v] + b0v, 0.f) * d0
                    + fmaxf(acc1[v] + b1v, 0.f) * d1;
            p += __shfl_xor(p, 1);
            p += __shfl_xor(p, 2);
            p += __shfl_xor(p, 4);
            p += __shfl_xor(p, 8);
            if ((l & 15) == 0) util[rbase + v] = p + dbv;
        }
    }
}

// out[p] = util[idx_b[p]] - util[idx_a[p]]
__global__ void pair_kernel(const float* __restrict__ util, const int* __restrict__ ia,
                            const int* __restrict__ ib, float* __restrict__ out) {
    int p = blockIdx.x * blockDim.x + threadIdx.x;
    if (p >= N_PAIRS) return;
    out[p] = util[ib[p]] - util[ia[p]];
}

extern "C" void kernel_launch(void* const* d_in, const int* in_sizes, int n_in,
                              void* d_out, int out_size, void* d_ws, size_t ws_size,
                              hipStream_t stream) {
    const float* x     = (const float*)d_in[0];
    const float* e     = (const float*)d_in[1];
    const float* knw1  = (const float*)d_in[2];
    const float* knb1  = (const float*)d_in[3];
    const float* root1 = (const float*)d_in[4];
    const float* bias1 = (const float*)d_in[5];
    const float* knw2  = (const float*)d_in[6];
    const float* knb2  = (const float*)d_in[7];
    const float* root2 = (const float*)d_in[8];
    const float* bias2 = (const float*)d_in[9];
    const float* dw    = (const float*)d_in[10];
    const float* db    = (const float*)d_in[11];
    const int*   ei    = (const int*)d_in[12];
    const int*   ia    = (const int*)d_in[13];
    const int*   ib    = (const int*)d_in[14];
    float* out = (float*)d_out;

    float* ws = (float*)d_ws;
    ushort* Gb     = (ushort*)ws;               // 6,400,000 ushorts
    ushort* H16    = (ushort*)(ws + 3200000);   // 640,000 ushorts
    float*  util   = ws + 3520000;              // 20,000 floats
    int*    cnt    = (int*)(ws + 3540000);      // 20,000
    int*    adjsrc = (int*)(ws + 3560000);      // 640,000 ints
    uint4*  adjEb  = (uint4*)(ws + 4200000);    // 640,000 uint4 -> ends 6,760,000
    ushort* wf1    = (ushort*)(ws + 6760000);   // 20,480 ushorts
    ushort* wf2    = (ushort*)(ws + 6765120);   // 20,480 ushorts

    int nblk_epi = (N_NODES / 16 + 3) / 4;           // 313
    int nblk_gat = (N_NODES * 64) / 256;             // 5000

    // ---- prep: zero cnt + build both Wfrag copies ----
    prep_kernel<<<159, 256, 0, stream>>>(cnt, knw1, knb1, root1, wf1,
                                         knw2, knb2, root2, wf2);
    fill_adj<<<(N_EDGES + 255) / 256, 256, 0, stream>>>(ei, e, cnt, adjsrc, adjEb);

    // ---- layer 1 (fp32 X) ----
    edge_gather_t<0><<<nblk_gat, 256, 0, stream>>>(x, nullptr, cnt, adjsrc, adjEb, Gb);
    epi_mfma<<<nblk_epi, 256, 0, stream>>>(Gb, wf1, bias1, dw, db, H16, util, 0);

    // ---- layer 2 (bf16 H) ----
    edge_gather_t<1><<<nblk_gat, 256, 0, stream>>>(nullptr, H16, cnt, adjsrc, adjEb, Gb);
    epi_mfma<<<nblk_epi, 256, 0, stream>>>(Gb, wf2, bias2, dw, db, H16, util, 1);

    // ---- pairs ----
    pair_kernel<<<(N_PAIRS + 255) / 256, 256, 0, stream>>>(util, ia, ib, out);
}